// Round 2
// baseline (40.546 us; speedup 1.0000x reference)
//
#include <hip/hip_runtime.h>

#define BB 8
#define NN 2048
#define TT 512
#define DD 32
#define SS (NN + TT)   // 2560 total nodes per batch
#define RPB 4          // rows per block (N % RPB == 0 -> no region straddle)

// ws layout (floats): rowL[B*SS] | rowR[B*SS] | colS[B*SS] | colT[B*SS]
//  rowL[b,r]: row score used for columns c <  N
//  rowR[b,r]: row score used for columns c >= N
//  colS[b,c]: col score (+bias) used for rows r <  N  (spatial rows)
//  colT[b,c]: col score (+bias) used for rows r >= N  (temporal rows)

__global__ __launch_bounds__(256) void precompute_scores(
    const float* __restrict__ sp,   // (B, N, D)
    const float* __restrict__ tp,   // (B, T, D)
    const float* __restrict__ w_ss, const float* __restrict__ b_ss,
    const float* __restrict__ w_tt, const float* __restrict__ b_tt,
    const float* __restrict__ w_st, const float* __restrict__ b_st,
    const float* __restrict__ w_ts, const float* __restrict__ b_ts,
    float* __restrict__ ws)
{
    int idx = blockIdx.x * blockDim.x + threadIdx.x;  // b*SS + i
    if (idx >= BB * SS) return;
    int b = idx / SS;
    int i = idx - b * SS;

    const float *v, *wl, *wr, *wcs, *wct;
    float bs, bt;
    if (i < NN) {
        // spatial node: rows use w_ss/w_st (lo half); cols use w_ss/w_ts (hi half)
        v   = sp + ((size_t)b * NN + i) * DD;
        wl  = w_ss;       wr  = w_st;
        wcs = w_ss + DD;  wct = w_ts + DD;
        bs  = b_ss[0];    bt  = b_ts[0];
    } else {
        // temporal node: rows use w_ts/w_tt (lo half); cols use w_st/w_tt (hi half)
        v   = tp + ((size_t)b * TT + (i - NN)) * DD;
        wl  = w_ts;       wr  = w_tt;
        wcs = w_st + DD;  wct = w_tt + DD;
        bs  = b_st[0];    bt  = b_tt[0];
    }

    float aL = 0.f, aR = 0.f, aS = 0.f, aT = 0.f;
#pragma unroll
    for (int d = 0; d < DD; ++d) {
        float x = v[d];
        aL = fmaf(x, wl[d],  aL);
        aR = fmaf(x, wr[d],  aR);
        aS = fmaf(x, wcs[d], aS);
        aT = fmaf(x, wct[d], aT);
    }

    float* rowL = ws;
    float* rowR = ws + 1 * BB * SS;
    float* colS = ws + 2 * BB * SS;
    float* colT = ws + 3 * BB * SS;
    rowL[idx] = aL;
    rowR[idx] = aR;
    colS[idx] = aS + bs;
    colT[idx] = aT + bt;
}

__device__ __forceinline__ float tanh_relu(float x) {
    float t = fmaxf(x, 0.f);
    // tanh(t) = 1 - 2/(exp(2t)+1); exact 0 at t=0
    float e = __expf(2.f * t);
    return fmaf(-2.f, __builtin_amdgcn_rcpf(e + 1.f), 1.f);
}

// One block per 4-row group (b, r0..r0+3); 640 threads, each thread:
// load col float4 once, write 4 rows' float4 (4-deep store ILP).
__global__ __launch_bounds__(640) void adj_kernel(
    const float* __restrict__ ws, float* __restrict__ out)
{
    const int RGPB = SS / RPB;     // row-groups per batch = 640
    int gid = blockIdx.x;          // b*RGPB + rg
    int b  = gid / RGPB;
    int rg = gid - b * RGPB;
    int r0 = rg * RPB;

    const float* rowL = ws;
    const float* rowR = ws + 1 * BB * SS;
    const float* colS = ws + 2 * BB * SS;
    const float* colT = ws + 3 * BB * SS;

    int base = b * SS + r0;        // index of first row's score / output row

    // col vector first (the global-latency op), row scores are uniform loads
    int c4 = threadIdx.x;          // 0..639, 4 columns each
    const float* col = ((r0 < NN) ? colS : colT) + (size_t)b * SS;
    float4 cv = ((const float4*)col)[c4];

    bool left = (c4 < NN / 4);     // uniform per wave (512 = 8*64)

    float rv0 = left ? rowL[base + 0] : rowR[base + 0];
    float rv1 = left ? rowL[base + 1] : rowR[base + 1];
    float rv2 = left ? rowL[base + 2] : rowR[base + 2];
    float rv3 = left ? rowL[base + 3] : rowR[base + 3];

    float4* o0 = (float4*)(out + (size_t)(base + 0) * SS) + c4;
    float4* o1 = (float4*)(out + (size_t)(base + 1) * SS) + c4;
    float4* o2 = (float4*)(out + (size_t)(base + 2) * SS) + c4;
    float4* o3 = (float4*)(out + (size_t)(base + 3) * SS) + c4;

    float4 v0, v1, v2, v3;
    v0.x = tanh_relu(rv0 + cv.x); v0.y = tanh_relu(rv0 + cv.y);
    v0.z = tanh_relu(rv0 + cv.z); v0.w = tanh_relu(rv0 + cv.w);
    v1.x = tanh_relu(rv1 + cv.x); v1.y = tanh_relu(rv1 + cv.y);
    v1.z = tanh_relu(rv1 + cv.z); v1.w = tanh_relu(rv1 + cv.w);
    v2.x = tanh_relu(rv2 + cv.x); v2.y = tanh_relu(rv2 + cv.y);
    v2.z = tanh_relu(rv2 + cv.z); v2.w = tanh_relu(rv2 + cv.w);
    v3.x = tanh_relu(rv3 + cv.x); v3.y = tanh_relu(rv3 + cv.y);
    v3.z = tanh_relu(rv3 + cv.z); v3.w = tanh_relu(rv3 + cv.w);

    *o0 = v0; *o1 = v1; *o2 = v2; *o3 = v3;
}

extern "C" void kernel_launch(void* const* d_in, const int* in_sizes, int n_in,
                              void* d_out, int out_size, void* d_ws, size_t ws_size,
                              hipStream_t stream) {
    const float* sp   = (const float*)d_in[0];
    const float* tp   = (const float*)d_in[1];
    const float* w_ss = (const float*)d_in[2];
    const float* b_ss = (const float*)d_in[3];
    const float* w_tt = (const float*)d_in[4];
    const float* b_tt = (const float*)d_in[5];
    const float* w_st = (const float*)d_in[6];
    const float* b_st = (const float*)d_in[7];
    const float* w_ts = (const float*)d_in[8];
    const float* b_ts = (const float*)d_in[9];
    float* out = (float*)d_out;
    float* ws  = (float*)d_ws;   // needs 4*B*SS*4 = 320 KB

    int nscore = BB * SS;  // 20480
    precompute_scores<<<(nscore + 255) / 256, 256, 0, stream>>>(
        sp, tp, w_ss, b_ss, w_tt, b_tt, w_st, b_st, w_ts, b_ts, ws);

    adj_kernel<<<(BB * SS) / RPB, 640, 0, stream>>>(ws, out);
}